// Round 1
// baseline (103.783 us; speedup 1.0000x reference)
//
#include <hip/hip_runtime.h>

// (B,N,D,H,K) = (8,128,256,128,8) — all fp32
#define PB 8
#define PN 128
#define PD 256
#define PH 128
#define PK 8
#define D2 (2*PD)  // 512

// ---------------------------------------------------------------------------
// k0: blocks 0..63 — transpose W1[h][d2] into W1t4[dq][h] where each float4
//     cell holds W1[h][4dq..4dq+3]. Coalesced loads (lane=d) and coalesced
//     float4 stores (lane=h) via a padded 32x32 LDS tile.
//     blocks 64..71 — Wq[h][k] = sum_d W2[d][h] q[k][d], bq[k] = b2 . q[k].
// ---------------------------------------------------------------------------
__global__ __launch_bounds__(256) void k0_prep(
        const float* __restrict__ W1, const float* __restrict__ W2,
        const float* __restrict__ b2, const float* __restrict__ q,
        float4* __restrict__ W1t4, float* __restrict__ Wq, float* __restrict__ bq)
{
    const int blk = blockIdx.x, t = threadIdx.x;
    if (blk < 64) {
        __shared__ float sm[32][33];
        const int h0 = (blk >> 4) * 32;       // 4 h-tiles
        const int d0 = (blk & 15) * 32;       // 16 d-tiles
        const int tx = t & 31, ty = t >> 5;   // ty in [0,8)
        #pragma unroll
        for (int r = 0; r < 4; ++r)
            sm[ty + 8 * r][tx] = W1[(h0 + ty + 8 * r) * D2 + d0 + tx];
        __syncthreads();
        const int hl = t & 31, dql = t >> 5;  // dql in [0,8)
        float4 w = make_float4(sm[hl][dql * 4 + 0], sm[hl][dql * 4 + 1],
                               sm[hl][dql * 4 + 2], sm[hl][dql * 4 + 3]);
        W1t4[((d0 >> 2) + dql) * PH + h0 + hl] = w;   // lanes consecutive in h
    } else {
        __shared__ float qs[PD];
        __shared__ float red[256];
        const int k = blk - 64;
        qs[t] = q[k * PD + t];
        __syncthreads();
        if (t < PH) {
            float acc = 0.f;
            #pragma unroll 4
            for (int d = 0; d < PD; ++d)
                acc = fmaf(W2[d * PH + t], qs[d], acc);   // coalesced over t=h
            Wq[t * PK + k] = acc;                          // [h][k]
        }
        red[t] = b2[t] * qs[t];
        __syncthreads();
        for (int st = 128; st > 0; st >>= 1) {
            if (t < st) red[t] += red[t + st];
            __syncthreads();
        }
        if (t == 0) bq[k] = red[0];
    }
}

// ---------------------------------------------------------------------------
// k1: 256 blocks = (b, part, 8-row group). No W staging in LDS: each lane
//     reads its h-column of W1t4 as coalesced float4 from L2 into registers.
//     4-row register blocking: 16 FMA per W load + 4 broadcast ds_read_b128.
//     part 0 -> Ai[b][n][h] (+b1), part 1 -> Ajt[b][h][n] (float4 store).
// ---------------------------------------------------------------------------
__global__ __launch_bounds__(256) void k1_proj(
        const float* __restrict__ E, const float* __restrict__ b1,
        const float4* __restrict__ W1t4,
        float* __restrict__ Ai, float* __restrict__ Ajt)
{
    __shared__ float es[8 * PD];              // 8 KB: this block's 8 E rows
    const int blk = blockIdx.x, t = threadIdx.x;
    const int b    = blk >> 5;
    const int part = (blk >> 4) & 1;
    const int ng   = blk & 15;                // 8-row group
    const int h    = t & (PH - 1);
    const int s    = t >> 7;                  // picks row-quad

    const float* eb = E + (b * PN + ng * 8) * PD;
    #pragma unroll
    for (int r = 0; r < 8; ++r) es[r * PD + t] = eb[r * PD + t];
    __syncthreads();

    const float4* wp = W1t4 + (part * 64) * PH + h;   // coalesced over lanes
    const float* e0 = es + (s * 4 + 0) * PD;          // wave-uniform: broadcast
    const float* e1 = e0 + PD;
    const float* e2 = e1 + PD;
    const float* e3 = e2 + PD;

    float a0 = 0.f, a1 = 0.f, a2 = 0.f, a3 = 0.f;
    #pragma unroll 4
    for (int dq = 0; dq < 64; ++dq) {         // 4 d's per iteration
        const float4 w  = wp[dq * PH];        // 16B/lane, 1KB/wave from L2
        const float4 p0 = *reinterpret_cast<const float4*>(e0 + dq * 4);
        const float4 p1 = *reinterpret_cast<const float4*>(e1 + dq * 4);
        const float4 p2 = *reinterpret_cast<const float4*>(e2 + dq * 4);
        const float4 p3 = *reinterpret_cast<const float4*>(e3 + dq * 4);
        a0 = fmaf(w.x, p0.x, a0); a0 = fmaf(w.y, p0.y, a0);
        a0 = fmaf(w.z, p0.z, a0); a0 = fmaf(w.w, p0.w, a0);
        a1 = fmaf(w.x, p1.x, a1); a1 = fmaf(w.y, p1.y, a1);
        a1 = fmaf(w.z, p1.z, a1); a1 = fmaf(w.w, p1.w, a1);
        a2 = fmaf(w.x, p2.x, a2); a2 = fmaf(w.y, p2.y, a2);
        a2 = fmaf(w.z, p2.z, a2); a2 = fmaf(w.w, p2.w, a2);
        a3 = fmaf(w.x, p3.x, a3); a3 = fmaf(w.y, p3.y, a3);
        a3 = fmaf(w.z, p3.z, a3); a3 = fmaf(w.w, p3.w, a3);
    }

    const int n0 = ng * 8 + s * 4;
    if (part == 0) {
        const float bb = b1[h];
        Ai[(b * PN + n0 + 0) * PH + h] = a0 + bb;   // coalesced over h
        Ai[(b * PN + n0 + 1) * PH + h] = a1 + bb;
        Ai[(b * PN + n0 + 2) * PH + h] = a2 + bb;
        Ai[(b * PN + n0 + 3) * PH + h] = a3 + bb;
    } else {
        *reinterpret_cast<float4*>(&Ajt[(b * PH + h) * PN + n0]) =
            make_float4(a0, a1, a2, a3);
    }
}

// ---------------------------------------------------------------------------
// k2: 256 blocks = (b, i-quad), 256 threads. All 8 k's fused (hidden computed
//     once) and 2 j's per thread: 16 accs, so the per-h LDS broadcasts +
//     Ajt load are amortized over 16 FMAs.
//     i = i0 + (t>>6), j in {t&63, (t&63)+64}.
// ---------------------------------------------------------------------------
__global__ __launch_bounds__(256) void k2_score(
        const float* __restrict__ Ai, const float* __restrict__ Ajt,
        const float* __restrict__ Wq, const float* __restrict__ bq,
        float* __restrict__ out)
{
    __shared__ float  ais[4 * PH];            // 2 KB: 4 Ai rows
    __shared__ float4 wqs[2 * PH];            // 4 KB: Wq[h][0..7] as 2 float4
    __shared__ float  bqs[PK];

    const int blk = blockIdx.x, t = threadIdx.x;
    const int b  = blk >> 5;                  // [0,8)
    const int ig = blk & 31;                  // i-quad
    const int i0 = ig * 4;
    const int il = t >> 6;                    // [0,4)
    const int jb = t & 63;

    ais[t]       = Ai[(b * PN + i0) * PH + t];
    ais[256 + t] = Ai[(b * PN + i0) * PH + 256 + t];
    wqs[t] = reinterpret_cast<const float4*>(Wq)[t];   // 256 float4 = all of Wq
    if (t < PK) bqs[t] = bq[t];
    __syncthreads();

    const float* ail = ais + il * PH;                  // broadcast reads
    const float* ajr = Ajt + b * PH * PN + jb;         // lane-contiguous per h

    float acc0[PK], acc1[PK];
    #pragma unroll
    for (int k = 0; k < PK; ++k) { acc0[k] = bqs[k]; acc1[k] = bqs[k]; }

    #pragma unroll 4
    for (int hh = 0; hh < PH; ++hh) {
        const float a  = ail[hh];                      // bcast b32
        const float g0 = ajr[hh * PN];                 // coalesced 256B
        const float g1 = ajr[hh * PN + 64];
        const float v0 = fmaxf(a + g0, 0.f);
        const float v1 = fmaxf(a + g1, 0.f);
        const float4 wA = wqs[hh * 2];                 // bcast b128
        const float4 wB = wqs[hh * 2 + 1];
        acc0[0] = fmaf(v0, wA.x, acc0[0]); acc0[1] = fmaf(v0, wA.y, acc0[1]);
        acc0[2] = fmaf(v0, wA.z, acc0[2]); acc0[3] = fmaf(v0, wA.w, acc0[3]);
        acc0[4] = fmaf(v0, wB.x, acc0[4]); acc0[5] = fmaf(v0, wB.y, acc0[5]);
        acc0[6] = fmaf(v0, wB.z, acc0[6]); acc0[7] = fmaf(v0, wB.w, acc0[7]);
        acc1[0] = fmaf(v1, wA.x, acc1[0]); acc1[1] = fmaf(v1, wA.y, acc1[1]);
        acc1[2] = fmaf(v1, wA.z, acc1[2]); acc1[3] = fmaf(v1, wA.w, acc1[3]);
        acc1[4] = fmaf(v1, wB.x, acc1[4]); acc1[5] = fmaf(v1, wB.y, acc1[5]);
        acc1[6] = fmaf(v1, wB.z, acc1[6]); acc1[7] = fmaf(v1, wB.w, acc1[7]);
    }

    const int i = i0 + il;
    #pragma unroll
    for (int k = 0; k < PK; ++k) {
        float s0 = 1.f / (1.f + __expf(-acc0[k]));
        float s1 = 1.f / (1.f + __expf(-acc1[k]));
        if (jb == i)      s0 = 0.f;
        if (jb + 64 == i) s1 = 0.f;
        float* orow = out + ((b * PK + k) * PN + i) * PN;
        orow[jb]      = s0;                            // coalesced over j
        orow[jb + 64] = s1;
    }
}

extern "C" void kernel_launch(void* const* d_in, const int* in_sizes, int n_in,
                              void* d_out, int out_size, void* d_ws, size_t ws_size,
                              hipStream_t stream) {
    const float* E  = (const float*)d_in[0];
    const float* W1 = (const float*)d_in[1];
    const float* b1 = (const float*)d_in[2];
    const float* W2 = (const float*)d_in[3];
    const float* b2 = (const float*)d_in[4];
    const float* q  = (const float*)d_in[5];

    float*  Ai   = (float*)d_ws;                   // B*N*H          (512 KB)
    float*  Ajt  = Ai + PB * PN * PH;              // B*H*N          (512 KB)
    float4* W1t4 = (float4*)(Ajt + PB * PH * PN);  // 128 dq x 128 h (256 KB, 16B-aligned)
    float*  Wq   = (float*)(W1t4 + 128 * PH);      // H*K
    float*  bq   = Wq + PH * PK;                   // K

    k0_prep<<<72,  256, 0, stream>>>(W1, W2, b2, q, W1t4, Wq, bq);
    k1_proj<<<256, 256, 0, stream>>>(E, b1, W1t4, Ai, Ajt);
    k2_score<<<256, 256, 0, stream>>>(Ai, Ajt, Wq, bq, (float*)d_out);
}

// Round 2
// 101.932 us; speedup vs baseline: 1.0182x; 1.0182x over previous
//
#include <hip/hip_runtime.h>

// (B,N,D,H,K) = (8,128,256,128,8) — all fp32
#define PB 8
#define PN 128
#define PD 256
#define PH 128
#define PK 8
#define D2 (2*PD)  // 512

// ---------------------------------------------------------------------------
// k0: blocks 0..63 — transpose W1[h][d2] into W1t4[dq][h]: each float4 cell
//     holds W1[h][4dq..4dq+3]. Coalesced loads (lane=d), coalesced float4
//     stores (lane=h) via padded 32x32 LDS tile.
//     blocks 64..71 — Wq[h][k] = sum_d W2[d][h] q[k][d]; bq[k] = b2 . q[k].
// ---------------------------------------------------------------------------
__global__ __launch_bounds__(256) void k0_prep(
        const float* __restrict__ W1, const float* __restrict__ W2,
        const float* __restrict__ b2, const float* __restrict__ q,
        float4* __restrict__ W1t4, float* __restrict__ Wq, float* __restrict__ bq)
{
    const int blk = blockIdx.x, t = threadIdx.x;
    if (blk < 64) {
        __shared__ float sm[32][33];
        const int h0 = (blk >> 4) * 32;       // 4 h-tiles
        const int d0 = (blk & 15) * 32;       // 16 d-tiles
        const int tx = t & 31, ty = t >> 5;   // ty in [0,8)
        #pragma unroll
        for (int r = 0; r < 4; ++r)
            sm[ty + 8 * r][tx] = W1[(h0 + ty + 8 * r) * D2 + d0 + tx];
        __syncthreads();
        const int hl = t & 31, dql = t >> 5;  // dql in [0,8)
        float4 w = make_float4(sm[hl][dql * 4 + 0], sm[hl][dql * 4 + 1],
                               sm[hl][dql * 4 + 2], sm[hl][dql * 4 + 3]);
        W1t4[((d0 >> 2) + dql) * PH + h0 + hl] = w;   // lanes consecutive in h
    } else {
        __shared__ float qs[PD];
        __shared__ float red[256];
        const int k = blk - 64;
        qs[t] = q[k * PD + t];
        __syncthreads();
        if (t < PH) {
            float acc = 0.f;
            #pragma unroll 4
            for (int d = 0; d < PD; ++d)
                acc = fmaf(W2[d * PH + t], qs[d], acc);   // coalesced over t=h
            Wq[t * PK + k] = acc;                          // [h][k]
        }
        red[t] = b2[t] * qs[t];
        __syncthreads();
        for (int st = 128; st > 0; st >>= 1) {
            if (t < st) red[t] += red[t + st];
            __syncthreads();
        }
        if (t == 0) bq[k] = red[0];
    }
}

// ---------------------------------------------------------------------------
// k1: 512 blocks = (b:8, part:2, rg:32), 4 E-rows per block. NO LDS, no
//     barriers. Thread (h = t&127, s = t>>7) owns 1 h-column x 2 rows.
//     W1t4 column: coalesced float4 from L2 (16B/lane, 1KB/wave).
//     E rows: wave-uniform (s uniform per wave) -> readfirstlane-hinted
//     broadcast/scalar loads. 8 FMA per 16B of W traffic.
//     part 0 -> Ai[b][n][h] (+b1, coalesced over h)
//     part 1 -> Ajt[b][h][n] (float2 over n)
// ---------------------------------------------------------------------------
__global__ __launch_bounds__(256) void k1_proj(
        const float* __restrict__ E, const float* __restrict__ b1,
        const float4* __restrict__ W1t4,
        float* __restrict__ Ai, float* __restrict__ Ajt)
{
    const int blk = blockIdx.x, t = threadIdx.x;
    const int b    = blk >> 6;
    const int part = (blk >> 5) & 1;
    const int rg   = blk & 31;
    const int h    = t & (PH - 1);
    const int s    = t >> 7;              // wave-uniform
    const int n    = rg * 4 + 2 * s;      // first of this thread's 2 rows

    const int ebase = __builtin_amdgcn_readfirstlane((b * PN + n) * PD);
    const float* e0 = E + ebase;          // uniform per wave -> s_load path
    const float* e1 = e0 + PD;
    const float4* wp = W1t4 + (part * 64) * PH + h;   // coalesced over lanes

    float a0 = 0.f, a1 = 0.f;
    #pragma unroll 8
    for (int dq = 0; dq < 64; ++dq) {
        const float4 w  = wp[dq * PH];    // 16B/lane from L2
        const float4 p0 = *reinterpret_cast<const float4*>(e0 + dq * 4);
        const float4 p1 = *reinterpret_cast<const float4*>(e1 + dq * 4);
        a0 = fmaf(w.x, p0.x, a0); a0 = fmaf(w.y, p0.y, a0);
        a0 = fmaf(w.z, p0.z, a0); a0 = fmaf(w.w, p0.w, a0);
        a1 = fmaf(w.x, p1.x, a1); a1 = fmaf(w.y, p1.y, a1);
        a1 = fmaf(w.z, p1.z, a1); a1 = fmaf(w.w, p1.w, a1);
    }

    if (part == 0) {
        const float bb = b1[h];
        Ai[(b * PN + n + 0) * PH + h] = a0 + bb;   // coalesced over h
        Ai[(b * PN + n + 1) * PH + h] = a1 + bb;
    } else {
        *reinterpret_cast<float2*>(&Ajt[(b * PH + h) * PN + n]) =
            make_float2(a0, a1);
    }
}

// ---------------------------------------------------------------------------
// k2: 256 blocks = (b:8, i-quad:32), 256 threads, NO LDS. All uniform
//     operands (Ai row, Wq, bq) read straight from global: Wq is 4KB
//     (L1-resident), Ai rows L1-hot; Ajt coalesced over jb. 16 accs per
//     thread: i = i0 + (t>>6), j in {t&63, (t&63)+64}, all 8 k fused.
// ---------------------------------------------------------------------------
__global__ __launch_bounds__(256) void k2_score(
        const float* __restrict__ Ai, const float* __restrict__ Ajt,
        const float4* __restrict__ Wq4, const float* __restrict__ bq,
        float* __restrict__ out)
{
    const int blk = blockIdx.x, t = threadIdx.x;
    const int b  = blk >> 5;                  // [0,8)
    const int i0 = (blk & 31) * 4;
    const int il = t >> 6;                    // [0,4), wave-uniform
    const int jb = t & 63;
    const int i  = i0 + il;

    const int aib = __builtin_amdgcn_readfirstlane((b * PN + i) * PH);
    const float* ai = Ai + aib;               // uniform per wave
    const float* aj = Ajt + b * PH * PN + jb; // lane-contiguous per h

    float acc0[PK], acc1[PK];
    const float q0 = bq[0], q1 = bq[1], q2 = bq[2], q3 = bq[3];
    const float q4 = bq[4], q5 = bq[5], q6 = bq[6], q7 = bq[7];
    acc0[0]=q0; acc0[1]=q1; acc0[2]=q2; acc0[3]=q3;
    acc0[4]=q4; acc0[5]=q5; acc0[6]=q6; acc0[7]=q7;
    acc1[0]=q0; acc1[1]=q1; acc1[2]=q2; acc1[3]=q3;
    acc1[4]=q4; acc1[5]=q5; acc1[6]=q6; acc1[7]=q7;

    #pragma unroll 8
    for (int hh = 0; hh < PH; ++hh) {
        const float a  = ai[hh];                   // uniform b32
        const float g0 = aj[hh * PN];              // coalesced 256B
        const float g1 = aj[hh * PN + 64];
        const float v0 = fmaxf(a + g0, 0.f);
        const float v1 = fmaxf(a + g1, 0.f);
        const float4 wA = Wq4[hh * 2];             // uniform b128, L1
        const float4 wB = Wq4[hh * 2 + 1];
        acc0[0] = fmaf(v0, wA.x, acc0[0]); acc0[1] = fmaf(v0, wA.y, acc0[1]);
        acc0[2] = fmaf(v0, wA.z, acc0[2]); acc0[3] = fmaf(v0, wA.w, acc0[3]);
        acc0[4] = fmaf(v0, wB.x, acc0[4]); acc0[5] = fmaf(v0, wB.y, acc0[5]);
        acc0[6] = fmaf(v0, wB.z, acc0[6]); acc0[7] = fmaf(v0, wB.w, acc0[7]);
        acc1[0] = fmaf(v1, wA.x, acc1[0]); acc1[1] = fmaf(v1, wA.y, acc1[1]);
        acc1[2] = fmaf(v1, wA.z, acc1[2]); acc1[3] = fmaf(v1, wA.w, acc1[3]);
        acc1[4] = fmaf(v1, wB.x, acc1[4]); acc1[5] = fmaf(v1, wB.y, acc1[5]);
        acc1[6] = fmaf(v1, wB.z, acc1[6]); acc1[7] = fmaf(v1, wB.w, acc1[7]);
    }

    #pragma unroll
    for (int k = 0; k < PK; ++k) {
        float s0 = 1.f / (1.f + __expf(-acc0[k]));
        float s1 = 1.f / (1.f + __expf(-acc1[k]));
        if (jb == i)      s0 = 0.f;
        if (jb + 64 == i) s1 = 0.f;
        float* orow = out + ((b * PK + k) * PN + i) * PN;
        orow[jb]      = s0;                        // coalesced over j
        orow[jb + 64] = s1;
    }
}

extern "C" void kernel_launch(void* const* d_in, const int* in_sizes, int n_in,
                              void* d_out, int out_size, void* d_ws, size_t ws_size,
                              hipStream_t stream) {
    const float* E  = (const float*)d_in[0];
    const float* W1 = (const float*)d_in[1];
    const float* b1 = (const float*)d_in[2];
    const float* W2 = (const float*)d_in[3];
    const float* b2 = (const float*)d_in[4];
    const float* q  = (const float*)d_in[5];

    float*  Ai   = (float*)d_ws;                   // B*N*H          (512 KB)
    float*  Ajt  = Ai + PB * PN * PH;              // B*H*N          (512 KB)
    float4* W1t4 = (float4*)(Ajt + PB * PH * PN);  // 128 dq x 128 h (256 KB)
    float*  Wq   = (float*)(W1t4 + 128 * PH);      // H*K (16B-aligned)
    float*  bq   = Wq + PH * PK;                   // K

    k0_prep<<<72,  256, 0, stream>>>(W1, W2, b2, q, W1t4, Wq, bq);
    k1_proj<<<512, 256, 0, stream>>>(E, b1, W1t4, Ai, Ajt);
    k2_score<<<256, 256, 0, stream>>>(Ai, Ajt, (const float4*)Wq, bq, (float*)d_out);
}